// Round 2
// baseline (4258.370 us; speedup 1.0000x reference)
//
#include <hip/hip_runtime.h>
#include <hip/hip_bf16.h>

#define NN 10000
#define NE 80000
#define PP 4
#define CC 128
#define NR (NN*PP)   // 40000 node rows
#define ER (NE*PP)   // 320000 edge rows
#define S1 136       // LDS row stride (u16) for bf16 K=128 rows: 68 dwords == 4 mod 32; 17 quads -> conflict-free b128
#define SF 132       // LDS row stride (f32) for f32 K=128 rows: 33 quads -> conflict-free b128

typedef unsigned short u16;
typedef unsigned int   u32;

__device__ inline float b2f(u16 v) { return __uint_as_float(((u32)v) << 16); }
__device__ inline float bfl(u32 u) { return __uint_as_float(u << 16); }
__device__ inline float bfh(u32 u) { return __uint_as_float(u & 0xffff0000u); }
__device__ inline u16 f2b(float f) {
    u32 x = __float_as_uint(f);
    return (u16)((x + 0x7fffu + ((x >> 16) & 1u)) >> 16);
}
__device__ inline void atomicMaxF(float* addr, float val) {
    if (val >= 0.f) atomicMax((int*)addr, __float_as_int(val));
    else            atomicMin((u32*)addr, __float_as_uint(val));
}

// acc = sum_k x[k] * WTrow[k], K=128, bf16 weight row in LDS
__device__ inline float mv128(const u16* WTrow, const float* x) {
    const uint4* w4 = (const uint4*)WTrow;
    float acc = 0.f;
#pragma unroll
    for (int j = 0; j < 16; ++j) {
        uint4 w = w4[j];
        const float* p = x + 8 * j;
        acc += p[0]*bfl(w.x) + p[1]*bfh(w.x) + p[2]*bfl(w.y) + p[3]*bfh(w.y)
             + p[4]*bfl(w.z) + p[5]*bfh(w.z) + p[6]*bfl(w.w) + p[7]*bfh(w.w);
    }
    return acc;
}
__device__ inline void mv128x2(const u16* WTrow, const float* x0, const float* x1,
                               float& a0, float& a1) {
    const uint4* w4 = (const uint4*)WTrow;
    float acc0 = 0.f, acc1 = 0.f;
#pragma unroll
    for (int j = 0; j < 16; ++j) {
        uint4 w = w4[j];
        float w0=bfl(w.x), w1=bfh(w.x), w2=bfl(w.y), w3=bfh(w.y);
        float w4f=bfl(w.z), w5=bfh(w.z), w6=bfl(w.w), w7=bfh(w.w);
        const float* p0 = x0 + 8 * j; const float* p1 = x1 + 8 * j;
        acc0 += p0[0]*w0 + p0[1]*w1 + p0[2]*w2 + p0[3]*w3 + p0[4]*w4f + p0[5]*w5 + p0[6]*w6 + p0[7]*w7;
        acc1 += p1[0]*w0 + p1[1]*w1 + p1[2]*w2 + p1[3]*w3 + p1[4]*w4f + p1[5]*w5 + p1[6]*w6 + p1[7]*w7;
    }
    a0 = acc0; a1 = acc1;
}
__device__ inline float mv256(const u16* WTrow, const float* x) {
    const uint4* w4 = (const uint4*)WTrow;
    float acc = 0.f;
#pragma unroll
    for (int j = 0; j < 32; ++j) {
        uint4 w = w4[j];
        const float* p = x + 8 * j;
        acc += p[0]*bfl(w.x) + p[1]*bfh(w.x) + p[2]*bfl(w.y) + p[3]*bfh(w.y)
             + p[4]*bfl(w.z) + p[5]*bfh(w.z) + p[6]*bfl(w.w) + p[7]*bfh(w.w);
    }
    return acc;
}
// f32 weight row in LDS
__device__ inline void mv128fx2(const float* Wrow, const float* x0, const float* x1,
                                float& a0, float& a1) {
    const float4* w4 = (const float4*)Wrow;
    float s0 = 0.f, s1 = 0.f;
#pragma unroll
    for (int j = 0; j < 32; ++j) {
        float4 w = w4[j];
        const float* p0 = x0 + 4 * j; const float* p1 = x1 + 4 * j;
        s0 += p0[0]*w.x + p0[1]*w.y + p0[2]*w.z + p0[3]*w.w;
        s1 += p1[0]*w.x + p1[1]*w.y + p1[2]*w.z + p1[3]*w.w;
    }
    a0 = s0; a1 = s1;
}

// ---------------- kernel 1: [Q|K|V|Qe] = h @ [Wq|Wk|Wv|eWq], f32 out ----------------
__global__ __launch_bounds__(512) void k_qkvqe(const float* __restrict__ h,
    const float* __restrict__ Wq, const float* __restrict__ Wk,
    const float* __restrict__ Wv, const float* __restrict__ eWq,
    float* __restrict__ out)
{
    __shared__ __align__(16) u16 WT[512 * S1];
    __shared__ float xs[2][128];
    const int t = threadIdx.x;
    {
        int sel = t >> 7, col = t & 127;
        const float* W = (sel == 0) ? Wq : (sel == 1) ? Wk : (sel == 2) ? Wv : eWq;
        u16* dp = &WT[t * S1];
        for (int k = 0; k < 128; ++k) dp[k] = f2b(W[k * 128 + col]);
    }
    __syncthreads();
    for (int base = blockIdx.x * 2; base < NR; base += gridDim.x * 2) {
        if (t < 256) xs[t >> 7][t & 127] = h[(base + (t >> 7)) * 128 + (t & 127)];
        __syncthreads();
        float a0, a1;
        mv128x2(&WT[t * S1], xs[0], xs[1], a0, a1);
        out[base * 512 + t] = a0;
        out[(base + 1) * 512 + t] = a1;
        __syncthreads();
    }
}

// ---------------- kernel 2: attention edges + fused Oe projection + BN-e stats ----------------
__global__ __launch_bounds__(256) void k_attn(const float* __restrict__ e,
    const int* __restrict__ src, const int* __restrict__ dst,
    const float* __restrict__ We, const float* __restrict__ Oe_w, const float* __restrict__ Oe_b,
    const float* __restrict__ qkvqe, float* __restrict__ wV, float* __restrict__ z,
    float* __restrict__ stats, float* __restrict__ out_e)
{
    __shared__ __align__(16) u16 WT[2 * 128 * S1];  // [0..127]=WeT, [128..255]=OeT
    __shared__ float es[2][128];
    __shared__ float sc[2][128];
    __shared__ float sh[2][8];
    const int t = threadIdx.x;
    {
        int sel = t >> 7, col = t & 127;
        const float* W = sel ? Oe_w : We;
        u16* dp = &WT[(sel * 128 + col) * S1];
        for (int k = 0; k < 128; ++k) dp[k] = f2b(W[k * 128 + col]);
    }
    __syncthreads();
    const int rs = t >> 7, c = t & 127;
    const float oeb = Oe_b[c];
    float s1 = 0.f, s2 = 0.f;
    for (int base = blockIdx.x * 2; base < ER; base += gridDim.x * 2) {
        int re = base + rs;
        int ei = re >> 2, p = re & 3;
        int srow = src[ei] * 4 + p, drow = dst[ei] * 4 + p;
        es[rs][c] = e[re * 128 + c];
        __syncthreads();
        float pe = mv128(&WT[c * S1], es[rs]);  // proj_e = e @ We (this channel)
        float scv = qkvqe[srow * 512 + 128 + c] * qkvqe[drow * 512 + c] * 0.25f + pe;
        sc[rs][c] = scv;
        __syncthreads();
        if (c < 8) {
            float hs = 0.f;
#pragma unroll
            for (int d2 = 0; d2 < 16; ++d2) hs += sc[rs][c * 16 + d2];
            hs = fminf(fmaxf(hs, -5.f), 5.f);
            float sv = expf(hs);
            sh[rs][c] = sv;
            atomicAdd(&z[drow * 8 + c], sv);
        }
        __syncthreads();
        float sv = sh[rs][c >> 4];
        atomicAdd(&wV[drow * 128 + c], qkvqe[srow * 512 + 256 + c] * sv);
        float ef = es[rs][c] + oeb + mv128(&WT[(128 + c) * S1], sc[rs]);
        out_e[re * 128 + c] = ef;
        s1 += ef; s2 += ef * ef;
        __syncthreads();
    }
    atomicAdd(&stats[256 + c], s1);
    atomicAdd(&stats[384 + c], s2);
}

// ---------------- kernel 3: enhance edges (k_diff f32-W, v_diff/repe bf16-W) -> atomic max ----------------
__global__ __launch_bounds__(384) void k_enh(const float* __restrict__ h, const float* __restrict__ e,
    const int* __restrict__ src, const int* __restrict__ dst,
    const float* __restrict__ eWk, const float* __restrict__ eWv, const float* __restrict__ eWre,
    const float* __restrict__ qkvqe, float* __restrict__ henh)
{
    __shared__ __align__(16) float Wkf[128 * SF];   // eWk^T in f32 (precision: feeds norms + max winner)
    __shared__ __align__(16) u16 WT[256 * S1];      // [0..127]=eWvT, [128..255]=eWreT (bf16)
    __shared__ float stage[6][128];                 // diff0,diff1,er0,er1,qd0,qd1
    __shared__ float kv[2][256];                    // [row][0..127]=k_diff, [128..255]=v_diff
    __shared__ float rp[2][128];                    // repe
    __shared__ float nrm[2][16];                    // [row][0..7]=nk, [8..15]=nq
    const int t = threadIdx.x;
    {
        int sel = t >> 7, col = t & 127;
        if (sel == 0)      for (int k = 0; k < 128; ++k) Wkf[col * SF + k] = eWk[k * 128 + col];
        else if (sel == 1) for (int k = 0; k < 128; ++k) WT[col * S1 + k] = f2b(eWv[k * 128 + col]);
        else               for (int k = 0; k < 128; ++k) WT[(128 + col) * S1 + k] = f2b(eWre[k * 128 + col]);
    }
    __syncthreads();
    const int sel = t >> 7;
    for (int base = blockIdx.x * 2; base < ER; base += gridDim.x * 2) {
        for (int s = t; s < 768; s += 384) {
            int g = s >> 7, cc = s & 127;
            int rs2 = g & 1;
            int re2 = base + rs2;
            int i2 = re2 >> 2, p2 = re2 & 3;
            float val;
            if (g < 2) {
                int sr = src[i2] * 4 + p2, dr = dst[i2] * 4 + p2;
                val = fmaxf(h[sr * 128 + cc] - h[dr * 128 + cc], 0.f);
            } else if (g < 4) {
                val = e[re2 * 128 + cc];
            } else {
                int dr = dst[i2] * 4 + p2;
                val = qkvqe[dr * 512 + 384 + cc];
            }
            stage[g][cc] = val;
        }
        __syncthreads();
        {
            int col = t & 127;
            float a0, a1;
            if (sel == 0) {
                mv128fx2(&Wkf[col * SF], stage[0], stage[1], a0, a1);
                kv[0][col] = a0; kv[1][col] = a1;                 // k_diff
            } else if (sel == 1) {
                mv128x2(&WT[col * S1], stage[0], stage[1], a0, a1);
                kv[0][128 + col] = a0; kv[1][128 + col] = a1;     // v_diff
            } else {
                mv128x2(&WT[(128 + col) * S1], stage[2], stage[3], a0, a1);
                rp[0][col] = a0; rp[1][col] = a1;                 // repe
            }
        }
        __syncthreads();
        if (t < 32) {
            int rs2 = t >> 4, q = (t >> 3) & 1, h8 = t & 7;
            float s = 0.f;
            if (q == 0) {
#pragma unroll
                for (int d2 = 0; d2 < 16; ++d2) { float v = kv[rs2][h8 * 16 + d2]; s += v * v; }
                nrm[rs2][h8] = sqrtf(s + 1e-12f);
            } else {
#pragma unroll
                for (int d2 = 0; d2 < 16; ++d2) { float v = stage[4 + rs2][h8 * 16 + d2]; s += v * v; }
                nrm[rs2][8 + h8] = sqrtf(s + 1e-12f);
            }
        }
        __syncthreads();
        if (t < 256) {
            int rs2 = t >> 7, c = t & 127, hh = c >> 4;
            int re2 = base + rs2;
            int i2 = re2 >> 2, p2 = re2 & 3;
            int dr = dst[i2] * 4 + p2;
            float scv = stage[4 + rs2][c] * kv[rs2][c] * (nrm[rs2][hh] * nrm[rs2][8 + hh] + 1e-6f) + rp[rs2][c];
            float msg = scv * kv[rs2][128 + c];
            atomicMaxF(&henh[dr * 128 + c], msg);
        }
        __syncthreads();
    }
}

// ---------------- kernel 4: combine h_attn + h_enh, Oh projection, residual, BN-h stats ----------------
__global__ __launch_bounds__(256) void k_comb(const float* __restrict__ h,
    const float* __restrict__ Oh_w, const float* __restrict__ Oh_b,
    const float* __restrict__ wV, const float* __restrict__ z, const float* __restrict__ henh,
    float* __restrict__ hf, float* __restrict__ stats)
{
    __shared__ __align__(16) u16 WT[128 * S1];
    __shared__ float xs[2][128];
    const int t = threadIdx.x;
    {
        int col = t & 127, half = t >> 7;
        for (int k = half * 64; k < half * 64 + 64; ++k) WT[col * S1 + k] = f2b(Oh_w[k * 128 + col]);
    }
    __syncthreads();
    const int rs = t >> 7, c = t & 127;
    const float ohb = Oh_b[c];
    float s1 = 0.f, s2 = 0.f;
    for (int base = blockIdx.x * 2; base < NR; base += gridDim.x * 2) {
        int r = base + rs;
        float hv = henh[r * 128 + c];
        u32 hb = __float_as_uint(hv);
        if (((hb >> 23) & 0xffu) == 0xffu) hv = 0.f;   // -inf/NaN (no in-edges) -> 0
        xs[rs][c] = wV[r * 128 + c] / (z[r * 8 + (c >> 4)] + 1e-6f) + hv;
        __syncthreads();
        float val = h[r * 128 + c] + ohb + mv128(&WT[c * S1], xs[rs]);
        hf[r * 128 + c] = val;
        s1 += val; s2 += val * val;
        __syncthreads();
    }
    atomicAdd(&stats[c], s1);
    atomicAdd(&stats[128 + c], s2);
}

// ---------------- kernel 5: BN scale/shift prep ----------------
__global__ void k_bnprep(const float* __restrict__ stats,
    const float* __restrict__ gh, const float* __restrict__ bh,
    const float* __restrict__ ge, const float* __restrict__ be, float* __restrict__ bnsc)
{
    int c = threadIdx.x;
    if (c < 128) {
        float m = stats[c] / (float)NR;
        float v = stats[128 + c] / (float)NR - m * m;
        float sc = gh[c] * rsqrtf(v + 1e-5f);
        bnsc[c] = sc; bnsc[128 + c] = bh[c] - m * sc;
        m = stats[256 + c] / (float)ER;
        v = stats[384 + c] / (float)ER - m * m;
        sc = ge[c] * rsqrtf(v + 1e-5f);
        bnsc[256 + c] = sc; bnsc[384 + c] = be[c] - m * sc;
    }
}

// ---------------- kernel 6: BN-h apply + FFN + residual -> out_h (f32) ----------------
__global__ __launch_bounds__(256) void k_ffn(const float* __restrict__ hf,
    const float* __restrict__ W1, const float* __restrict__ b1,
    const float* __restrict__ W2, const float* __restrict__ b2,
    const float* __restrict__ bnsc, float* __restrict__ out_h)
{
    __shared__ __align__(16) u16 W1T[256 * S1];
    __shared__ __align__(16) u16 W2T[128 * (2 * S1)];
    __shared__ float xn[128];
    __shared__ float tt[256];
    __shared__ float scs[128], shs[128];
    const int t = threadIdx.x;
    {
        for (int k = 0; k < 128; ++k) W1T[t * S1 + k] = f2b(W1[k * 256 + t]);
        int col = t & 127, half = t >> 7;
        for (int kk = 0; kk < 128; ++kk) { int k = half * 128 + kk; W2T[col * (2 * S1) + k] = f2b(W2[k * 128 + col]); }
        if (t < 128) { scs[t] = bnsc[t]; shs[t] = bnsc[128 + t]; }
    }
    __syncthreads();
    const float bb1 = b1[t];
    const float bb2 = (t < 128) ? b2[t] : 0.f;
    for (int r = blockIdx.x; r < NR; r += gridDim.x) {
        if (t < 128) xn[t] = hf[r * 128 + t] * scs[t] + shs[t];
        __syncthreads();
        tt[t] = fmaxf(bb1 + mv128(&W1T[t * S1], xn), 0.f);
        __syncthreads();
        if (t < 128) {
            float o = xn[t] + bb2 + mv256(&W2T[t * (2 * S1)], tt);
            out_h[r * 128 + t] = o;
        }
        __syncthreads();
    }
}

// ---------------- kernel 7: BN-e apply in place on d_out e-region (f32, float4) ----------------
__global__ __launch_bounds__(256) void k_bne(float* __restrict__ out_e, const float* __restrict__ bnsc)
{
    __shared__ float scs[128], shs[128];
    const int t = threadIdx.x;
    if (t < 128) { scs[t] = bnsc[256 + t]; shs[t] = bnsc[384 + t]; }
    __syncthreads();
    int idx = blockIdx.x * 256 + t;                // one float4 per thread
    const int total = ER * 128 / 4;                // 10,240,000
    for (; idx < total; idx += gridDim.x * 256) {
        float4 v = ((const float4*)out_e)[idx];
        int c0 = (idx * 4) & 127;
        v.x = v.x * scs[c0 + 0] + shs[c0 + 0];
        v.y = v.y * scs[c0 + 1] + shs[c0 + 1];
        v.z = v.z * scs[c0 + 2] + shs[c0 + 2];
        v.w = v.w * scs[c0 + 3] + shs[c0 + 3];
        ((float4*)out_e)[idx] = v;
    }
}

extern "C" void kernel_launch(void* const* d_in, const int* in_sizes, int n_in,
                              void* d_out, int out_size, void* d_ws, size_t ws_size,
                              hipStream_t stream)
{
    const float* h    = (const float*)d_in[0];
    const float* e    = (const float*)d_in[1];
    const int* src    = (const int*)d_in[2];
    const int* dst    = (const int*)d_in[3];
    const float* Wq   = (const float*)d_in[4];
    const float* Wk   = (const float*)d_in[5];
    const float* Wv   = (const float*)d_in[6];
    const float* We   = (const float*)d_in[7];
    const float* eWq  = (const float*)d_in[8];
    const float* eWk  = (const float*)d_in[9];
    const float* eWv  = (const float*)d_in[10];
    const float* eWre = (const float*)d_in[11];
    const float* Oh_w = (const float*)d_in[12];
    const float* Oh_b = (const float*)d_in[13];
    const float* Oe_w = (const float*)d_in[14];
    const float* Oe_b = (const float*)d_in[15];
    const float* bnhg = (const float*)d_in[16];
    const float* bnhb = (const float*)d_in[17];
    const float* bneg = (const float*)d_in[18];
    const float* bneb = (const float*)d_in[19];
    const float* W1   = (const float*)d_in[20];
    const float* b1   = (const float*)d_in[21];
    const float* W2   = (const float*)d_in[22];
    const float* b2   = (const float*)d_in[23];

    float* out_h = (float*)d_out;
    float* out_e = out_h + (size_t)NR * 128;

    char* w = (char*)d_ws;
    float* qkvqe = (float*)(w);                         // NR*512 f32  = 81,920,000 B
    float* wV    = (float*)(w + 81920000);              // NR*128 f32  = 20,480,000 B
    float* z     = (float*)(w + 102400000);             // NR*8  f32   =  1,280,000 B
    float* henh  = (float*)(w + 103680000);             // NR*128 f32  = 20,480,000 B
    float* hf    = (float*)(w + 124160000);             // NR*128 f32  = 20,480,000 B
    float* stats = (float*)(w + 144640000);             // 512 f32
    float* bnsc  = (float*)(w + 144642048);             // 512 f32

    hipMemsetAsync(wV,    0,    20480000, stream);
    hipMemsetAsync(z,     0,    1280000,  stream);
    hipMemsetAsync(stats, 0,    2048,     stream);
    hipMemsetAsync(henh,  0xFF, 20480000, stream);      // -NaN: identity for atomicMaxF, filtered by finite check

    k_qkvqe<<<256, 512, 0, stream>>>(h, Wq, Wk, Wv, eWq, qkvqe);
    k_attn <<<1024, 256, 0, stream>>>(e, src, dst, We, Oe_w, Oe_b, qkvqe, wV, z, stats, out_e);
    k_enh  <<<256, 384, 0, stream>>>(h, e, src, dst, eWk, eWv, eWre, qkvqe, henh);
    k_comb <<<1024, 256, 0, stream>>>(h, Oh_w, Oh_b, wV, z, henh, hf, stats);
    k_bnprep<<<1, 128, 0, stream>>>(stats, bnhg, bnhb, bneg, bneb, bnsc);
    k_ffn  <<<256, 256, 0, stream>>>(hf, W1, b1, W2, b2, bnsc, out_h);
    k_bne  <<<40000, 256, 0, stream>>>(out_e, bnsc);
}